// Round 2
// baseline (1997.801 us; speedup 1.0000x reference)
//
#include <hip/hip_runtime.h>

#define BB 8
#define NN 256
#define FF 64

// ---------------------------------------------------------------------------
// pq: P[r] = be + x[r]@We[0:64], Q[r] = x[r]@We[64:128].  4 rows/block.
// ---------------------------------------------------------------------------
__global__ __launch_bounds__(256) void pq_kernel(
    const float* __restrict__ x, const float* __restrict__ We,
    const float* __restrict__ be, float* __restrict__ P, float* __restrict__ Q)
{
    const int rl = threadIdx.x >> 6, f = threadIdx.x & 63;
    const int r = blockIdx.x * 4 + rl;
    __shared__ float xs[4][FF];
    xs[rl][f] = x[r * FF + f];
    __syncthreads();
    float p = be[f], q = 0.f;
#pragma unroll
    for (int k = 0; k < FF; ++k) {
        const float xv = xs[rl][k];
        p = fmaf(xv, We[k * FF + f], p);
        q = fmaf(xv, We[(FF + k) * FF + f], q);
    }
    P[r * FF + f] = p;
    Q[r * FF + f] = q;
}

// ---------------------------------------------------------------------------
// fused node-update + pq for layers 1 and 2 + zero v.  4 rows/block.
// x1 = relu([x,agg]@Wn0 + bn0); P1/Q1 = x1@We1 (+be1); P2/Q2 = x1@We2 (+be2)
// x1 never hits global.
// ---------------------------------------------------------------------------
__global__ __launch_bounds__(256) void nodepq_kernel(
    const float* __restrict__ x, const float* __restrict__ agg,
    const float* __restrict__ Wn, const float* __restrict__ bn,
    const float* __restrict__ We1, const float* __restrict__ be1,
    const float* __restrict__ We2, const float* __restrict__ be2,
    float* __restrict__ P1, float* __restrict__ Q1,
    float* __restrict__ P2, float* __restrict__ Q2, float* __restrict__ v)
{
    const int rl = threadIdx.x >> 6, f = threadIdx.x & 63;
    const int r = blockIdx.x * 4 + rl;
    __shared__ float s[4][2 * FF];
    __shared__ float x1s[4][FF];
    s[rl][f]      = x[r * FF + f];
    s[rl][FF + f] = agg[r * FF + f];
    if (blockIdx.x == 0) {  // zero v for edge12's atomics (next dispatch)
        v[threadIdx.x] = 0.f;
        v[256 + threadIdx.x] = 0.f;
    }
    __syncthreads();
    float a = bn[f];
#pragma unroll
    for (int k = 0; k < 2 * FF; ++k) a = fmaf(s[rl][k], Wn[k * FF + f], a);
    x1s[rl][f] = fmaxf(a, 0.f);
    __syncthreads();
    float p1 = be1[f], q1 = 0.f, p2 = be2[f], q2 = 0.f;
#pragma unroll
    for (int k = 0; k < FF; ++k) {
        const float xv = x1s[rl][k];
        p1 = fmaf(xv, We1[k * FF + f], p1);
        q1 = fmaf(xv, We1[(FF + k) * FF + f], q1);
        p2 = fmaf(xv, We2[k * FF + f], p2);
        q2 = fmaf(xv, We2[(FF + k) * FF + f], q2);
    }
    P1[r * FF + f] = p1;  Q1[r * FF + f] = q1;
    P2[r * FF + f] = p2;  Q2[r * FF + f] = q2;
}

// ---------------------------------------------------------------------------
// layer-0 edge kernel: one block per (b,i) row.  In-place on e_attr.
// Register-prefetch pipeline, conflict-free j mapping (j = 2tj + 64m + p).
// Writes e_out row and agg[b,i] = (sum_j e_new)/deg.
// ---------------------------------------------------------------------------
__global__ __launch_bounds__(256, 3) void edge0_kernel(
    const float* __restrict__ e_in, const float* __restrict__ Wc,
    const float* __restrict__ P, const float* __restrict__ Q,
    const int* __restrict__ A, float* __restrict__ e_out,
    float* __restrict__ agg)
{
    __shared__ float Wl[FF * FF];      // 16 KB
    __shared__ float eb[2][16 * NN];   // 32 KB double buffer, [kk][j]
    __shared__ float Al[NN];
    __shared__ float Pl[FF];
    __shared__ float red[FF];
    __shared__ float degsh;

    const int tid = threadIdx.x;
    const int bi  = blockIdx.x;
    const int b   = bi >> 8;
    const int tj  = tid & 31, tf = tid >> 5;
    const int f0  = tf * 8;

    {
        const float4* Ws = (const float4*)Wc;
        float4*       Wd = (float4*)Wl;
#pragma unroll
        for (int m = 0; m < 4; ++m) Wd[tid + m * 256] = Ws[tid + m * 256];
    }
    Al[tid] = (float)A[bi * NN + tid];
    if (tid < FF) { Pl[tid] = P[bi * FF + tid]; red[tid] = 0.f; }

    const float*  erow = e_in + (size_t)bi * NN * FF;
    const float4* src  = (const float4*)(erow + tid * FF);

    float4 ld[4];
#pragma unroll
    for (int m = 0; m < 4; ++m) ld[m] = src[m];  // chunk 0
#pragma unroll
    for (int m = 0; m < 4; ++m) {                // store chunk 0 -> eb[0]
        eb[0][(4 * m + 0) * NN + tid] = ld[m].x;
        eb[0][(4 * m + 1) * NN + tid] = ld[m].y;
        eb[0][(4 * m + 2) * NN + tid] = ld[m].z;
        eb[0][(4 * m + 3) * NN + tid] = ld[m].w;
    }

    float acc[8][8];
#pragma unroll
    for (int a = 0; a < 8; ++a)
#pragma unroll
        for (int c = 0; c < 8; ++c) acc[a][c] = 0.f;

    for (int kc = 0; kc < 4; ++kc) {
        __syncthreads();
        if (kc == 0 && tid < 64) {  // deg after Al is visible
            float sd = Al[tid] + Al[tid + 64] + Al[tid + 128] + Al[tid + 192];
#pragma unroll
            for (int off = 32; off > 0; off >>= 1) sd += __shfl_down(sd, off);
            if (tid == 0) degsh = fmaxf(sd, 1.0f);
        }
        if (kc < 3) {  // prefetch next chunk; latency hidden under compute
#pragma unroll
            for (int m = 0; m < 4; ++m) ld[m] = src[(kc + 1) * 4 + m];
        }
        const float* ebc = eb[kc & 1];
#pragma unroll
        for (int kk = 0; kk < 16; ++kk) {
            const int k = kc * 16 + kk;
            const float4 w0 = *(const float4*)&Wl[k * FF + f0];
            const float4 w1 = *(const float4*)&Wl[k * FF + f0 + 4];
            const float wv[8] = {w0.x, w0.y, w0.z, w0.w, w1.x, w1.y, w1.z, w1.w};
#pragma unroll
            for (int m = 0; m < 4; ++m) {
                const float2 ev = *(const float2*)&ebc[kk * NN + 2 * tj + 64 * m];
#pragma unroll
                for (int ff = 0; ff < 8; ++ff) {
                    acc[2 * m][ff]     = fmaf(ev.x, wv[ff], acc[2 * m][ff]);
                    acc[2 * m + 1][ff] = fmaf(ev.y, wv[ff], acc[2 * m + 1][ff]);
                }
            }
        }
        if (kc < 3) {  // store prefetched chunk into other buffer
            float* ebn = eb[(kc + 1) & 1];
#pragma unroll
            for (int m = 0; m < 4; ++m) {
                ebn[(4 * m + 0) * NN + tid] = ld[m].x;
                ebn[(4 * m + 1) * NN + tid] = ld[m].y;
                ebn[(4 * m + 2) * NN + tid] = ld[m].z;
                ebn[(4 * m + 3) * NN + tid] = ld[m].w;
            }
        }
    }

    // epilogue (all global reads of this row retired before last barrier)
    float psum[8];
#pragma unroll
    for (int ff = 0; ff < 8; ++ff) psum[ff] = 0.f;
    const float* Qb   = Q + (size_t)b * NN * FF;
    float*       orow = e_out + (size_t)bi * NN * FF;
#pragma unroll
    for (int m = 0; m < 4; ++m)
#pragma unroll
        for (int p = 0; p < 2; ++p) {
            const int j  = 2 * tj + 64 * m + p;
            const int jj = 2 * m + p;
            const float a  = Al[j];
            const float4 q0 = *(const float4*)(Qb + j * FF + f0);
            const float4 q1 = *(const float4*)(Qb + j * FF + f0 + 4);
            const float qv[8] = {q0.x, q0.y, q0.z, q0.w, q1.x, q1.y, q1.z, q1.w};
            float r[8];
#pragma unroll
            for (int ff = 0; ff < 8; ++ff) {
                r[ff] = fmaxf(acc[jj][ff] + Pl[f0 + ff] + qv[ff], 0.f) * a;
                psum[ff] += r[ff];
            }
            *(float4*)(orow + j * FF + f0)     = make_float4(r[0], r[1], r[2], r[3]);
            *(float4*)(orow + j * FF + f0 + 4) = make_float4(r[4], r[5], r[6], r[7]);
        }
#pragma unroll
    for (int ff = 0; ff < 8; ++ff) atomicAdd(&red[f0 + ff], psum[ff]);
    __syncthreads();
    if (tid < FF) agg[bi * FF + tid] = red[tid] / degsh;
}

// ---------------------------------------------------------------------------
// fused layers 1+2: per row i, GEMM1 (e1@Wc1, epilogue P1/Q1/A) entirely in
// registers, then GEMM2 via LDS chunk round-trip, reduce to v (atomics).
// e2 never touches HBM.
// ---------------------------------------------------------------------------
__global__ __launch_bounds__(256, 3) void edge12_kernel(
    const float* __restrict__ e_in,
    const float* __restrict__ Wc1, const float* __restrict__ Wc2,
    const float* __restrict__ P1, const float* __restrict__ Q1,
    const float* __restrict__ P2, const float* __restrict__ Q2,
    const int* __restrict__ A, float* __restrict__ v)
{
    __shared__ float Wl[FF * FF];
    __shared__ float eb[2][16 * NN];
    __shared__ float Al[NN];
    __shared__ float Pl1[FF], Pl2[FF];
    __shared__ float red[FF];

    const int tid = threadIdx.x;
    const int bi  = blockIdx.x;
    const int b   = bi >> 8;
    const int tj  = tid & 31, tf = tid >> 5;
    const int f0  = tf * 8;

    {
        const float4* Ws = (const float4*)Wc1;
        float4*       Wd = (float4*)Wl;
#pragma unroll
        for (int m = 0; m < 4; ++m) Wd[tid + m * 256] = Ws[tid + m * 256];
    }
    Al[tid] = (float)A[bi * NN + tid];
    if (tid < FF) { Pl1[tid] = P1[bi * FF + tid]; Pl2[tid] = P2[bi * FF + tid]; red[tid] = 0.f; }

    const float*  erow = e_in + (size_t)bi * NN * FF;
    const float4* src  = (const float4*)(erow + tid * FF);

    float4 ld[4];
#pragma unroll
    for (int m = 0; m < 4; ++m) ld[m] = src[m];
#pragma unroll
    for (int m = 0; m < 4; ++m) {
        eb[0][(4 * m + 0) * NN + tid] = ld[m].x;
        eb[0][(4 * m + 1) * NN + tid] = ld[m].y;
        eb[0][(4 * m + 2) * NN + tid] = ld[m].z;
        eb[0][(4 * m + 3) * NN + tid] = ld[m].w;
    }

    float acc[8][8];  // GEMM1 accumulator, becomes r1 (e2 fragment) after epilogue1
#pragma unroll
    for (int a = 0; a < 8; ++a)
#pragma unroll
        for (int c = 0; c < 8; ++c) acc[a][c] = 0.f;

    for (int kc = 0; kc < 4; ++kc) {
        __syncthreads();
        if (kc < 3) {
#pragma unroll
            for (int m = 0; m < 4; ++m) ld[m] = src[(kc + 1) * 4 + m];
        }
        const float* ebc = eb[kc & 1];
#pragma unroll
        for (int kk = 0; kk < 16; ++kk) {
            const int k = kc * 16 + kk;
            const float4 w0 = *(const float4*)&Wl[k * FF + f0];
            const float4 w1 = *(const float4*)&Wl[k * FF + f0 + 4];
            const float wv[8] = {w0.x, w0.y, w0.z, w0.w, w1.x, w1.y, w1.z, w1.w};
#pragma unroll
            for (int m = 0; m < 4; ++m) {
                const float2 ev = *(const float2*)&ebc[kk * NN + 2 * tj + 64 * m];
#pragma unroll
                for (int ff = 0; ff < 8; ++ff) {
                    acc[2 * m][ff]     = fmaf(ev.x, wv[ff], acc[2 * m][ff]);
                    acc[2 * m + 1][ff] = fmaf(ev.y, wv[ff], acc[2 * m + 1][ff]);
                }
            }
        }
        if (kc < 3) {
            float* ebn = eb[(kc + 1) & 1];
#pragma unroll
            for (int m = 0; m < 4; ++m) {
                ebn[(4 * m + 0) * NN + tid] = ld[m].x;
                ebn[(4 * m + 1) * NN + tid] = ld[m].y;
                ebn[(4 * m + 2) * NN + tid] = ld[m].z;
                ebn[(4 * m + 3) * NN + tid] = ld[m].w;
            }
        }
    }

    // epilogue 1: acc -> e2 fragment (in place)
    {
        const float* Q1b = Q1 + (size_t)b * NN * FF;
#pragma unroll
        for (int m = 0; m < 4; ++m)
#pragma unroll
            for (int p = 0; p < 2; ++p) {
                const int j  = 2 * tj + 64 * m + p;
                const int jj = 2 * m + p;
                const float a  = Al[j];
                const float4 q0 = *(const float4*)(Q1b + j * FF + f0);
                const float4 q1 = *(const float4*)(Q1b + j * FF + f0 + 4);
                const float qv[8] = {q0.x, q0.y, q0.z, q0.w, q1.x, q1.y, q1.z, q1.w};
#pragma unroll
                for (int ff = 0; ff < 8; ++ff)
                    acc[jj][ff] = fmaxf(acc[jj][ff] + Pl1[f0 + ff] + qv[ff], 0.f) * a;
            }
    }
    __syncthreads();  // Wl (W1) and eb now free

    {   // stage W2
        const float4* Ws = (const float4*)Wc2;
        float4*       Wd = (float4*)Wl;
#pragma unroll
        for (int m = 0; m < 4; ++m) Wd[tid + m * 256] = Ws[tid + m * 256];
    }
    // store e2 chunk 0 (k2 in [0,16) -> waves with tf in {0,1})
    if (tf < 2) {
#pragma unroll
        for (int m = 0; m < 4; ++m)
#pragma unroll
            for (int ff = 0; ff < 8; ++ff) {
                float2 t = make_float2(acc[2 * m][ff], acc[2 * m + 1][ff]);
                *(float2*)&eb[0][((tf & 1) * 8 + ff) * NN + 2 * tj + 64 * m] = t;
            }
    }

    float acc2[8][8];
#pragma unroll
    for (int a = 0; a < 8; ++a)
#pragma unroll
        for (int c = 0; c < 8; ++c) acc2[a][c] = 0.f;
    __syncthreads();

    for (int c = 0; c < 4; ++c) {
        const float* ebc = eb[c & 1];
#pragma unroll
        for (int kk = 0; kk < 16; ++kk) {
            const int k2 = c * 16 + kk;
            const float4 w0 = *(const float4*)&Wl[k2 * FF + f0];
            const float4 w1 = *(const float4*)&Wl[k2 * FF + f0 + 4];
            const float wv[8] = {w0.x, w0.y, w0.z, w0.w, w1.x, w1.y, w1.z, w1.w};
#pragma unroll
            for (int m = 0; m < 4; ++m) {
                const float2 ev = *(const float2*)&ebc[kk * NN + 2 * tj + 64 * m];
#pragma unroll
                for (int ff = 0; ff < 8; ++ff) {
                    acc2[2 * m][ff]     = fmaf(ev.x, wv[ff], acc2[2 * m][ff]);
                    acc2[2 * m + 1][ff] = fmaf(ev.y, wv[ff], acc2[2 * m + 1][ff]);
                }
            }
        }
        if (c < 3 && (tf >> 1) == c + 1) {  // wave c+1 stores its e2 chunk
#pragma unroll
            for (int m = 0; m < 4; ++m)
#pragma unroll
                for (int ff = 0; ff < 8; ++ff) {
                    float2 t = make_float2(acc[2 * m][ff], acc[2 * m + 1][ff]);
                    *(float2*)&eb[(c + 1) & 1][((tf & 1) * 8 + ff) * NN + 2 * tj + 64 * m] = t;
                }
        }
        __syncthreads();
    }

    // epilogue 2: reduce e3 over j into red, then v
    float psum[8];
#pragma unroll
    for (int ff = 0; ff < 8; ++ff) psum[ff] = 0.f;
    const float* Q2b = Q2 + (size_t)b * NN * FF;
#pragma unroll
    for (int m = 0; m < 4; ++m)
#pragma unroll
        for (int p = 0; p < 2; ++p) {
            const int j  = 2 * tj + 64 * m + p;
            const int jj = 2 * m + p;
            const float a  = Al[j];
            const float4 q0 = *(const float4*)(Q2b + j * FF + f0);
            const float4 q1 = *(const float4*)(Q2b + j * FF + f0 + 4);
            const float qv[8] = {q0.x, q0.y, q0.z, q0.w, q1.x, q1.y, q1.z, q1.w};
#pragma unroll
            for (int ff = 0; ff < 8; ++ff)
                psum[ff] += fmaxf(acc2[jj][ff] + Pl2[f0 + ff] + qv[ff], 0.f) * a;
        }
#pragma unroll
    for (int ff = 0; ff < 8; ++ff) atomicAdd(&red[f0 + ff], psum[ff]);
    __syncthreads();
    if (tid < FF) atomicAdd(&v[b * FF + tid], red[tid]);
}

// ---------------------------------------------------------------------------
// head: v/65536 -> relu(@W1+b1) -> relu(@W2+b2) -> @W3+b3
// ---------------------------------------------------------------------------
__global__ __launch_bounds__(64) void head_kernel(
    const float* __restrict__ vsum, const float* __restrict__ W1,
    const float* __restrict__ b1, const float* __restrict__ W2,
    const float* __restrict__ b2, const float* __restrict__ W3,
    const float* __restrict__ b3, float* __restrict__ out)
{
    const int f = threadIdx.x;
    __shared__ float hv[BB][FF];
    __shared__ float h1[BB][FF];
#pragma unroll
    for (int b = 0; b < BB; ++b) hv[b][f] = vsum[b * FF + f] * (1.0f / 65536.0f);
    __syncthreads();
#pragma unroll
    for (int b = 0; b < BB; ++b) {
        float acc = b1[f];
#pragma unroll
        for (int k = 0; k < FF; ++k) acc = fmaf(hv[b][k], W1[k * FF + f], acc);
        h1[b][f] = fmaxf(acc, 0.f);
    }
    __syncthreads();
#pragma unroll
    for (int b = 0; b < BB; ++b) {
        float acc = b2[f];
#pragma unroll
        for (int k = 0; k < FF; ++k) acc = fmaf(h1[b][k], W2[k * FF + f], acc);
        hv[b][f] = fmaxf(acc, 0.f);
    }
    __syncthreads();
#pragma unroll
    for (int b = 0; b < BB; ++b) {
        float p = hv[b][f] * W3[f];
#pragma unroll
        for (int off = 32; off > 0; off >>= 1) p += __shfl_down(p, off);
        if (f == 0) out[b] = p + b3[0];
    }
}

// ---------------------------------------------------------------------------
extern "C" void kernel_launch(void* const* d_in, const int* in_sizes, int n_in,
                              void* d_out, int out_size, void* d_ws, size_t ws_size,
                              hipStream_t stream)
{
    const int*   A      = (const int*)d_in[0];
    const float* x      = (const float*)d_in[1];
    float*       e_attr = (float*)d_in[2];  // in-place (harness restores)

    const float* We0 = (const float*)d_in[3];
    const float* be0 = (const float*)d_in[4];
    const float* Wn0 = (const float*)d_in[5];
    const float* bn0 = (const float*)d_in[6];
    const float* We1 = (const float*)d_in[7];
    const float* be1 = (const float*)d_in[8];
    const float* We2 = (const float*)d_in[11];
    const float* be2 = (const float*)d_in[12];
    const float* W1 = (const float*)d_in[15];
    const float* b1 = (const float*)d_in[16];
    const float* W2 = (const float*)d_in[17];
    const float* b2 = (const float*)d_in[18];
    const float* W3 = (const float*)d_in[19];
    const float* b3 = (const float*)d_in[20];
    float* out = (float*)d_out;
    (void)in_sizes; (void)n_in; (void)out_size; (void)ws_size;

    const int R = BB * NN;  // 2048 rows
    float* P1  = (float*)d_ws;        // also P0
    float* Q1  = P1 + R * FF;         // also Q0
    float* P2  = Q1 + R * FF;
    float* Q2  = P2 + R * FF;
    float* agg = Q2 + R * FF;
    float* v   = agg + R * FF;        // 512 floats

    // layer 0
    pq_kernel<<<R / 4, 256, 0, stream>>>(x, We0, be0, P1, Q1);
    edge0_kernel<<<R, 256, 0, stream>>>(e_attr, We0 + 2 * FF * FF, P1, Q1, A,
                                        e_attr, agg);
    // node update + P/Q for layers 1,2 + zero v
    nodepq_kernel<<<R / 4, 256, 0, stream>>>(x, agg, Wn0, bn0, We1, be1, We2, be2,
                                             P1, Q1, P2, Q2, v);
    // fused layers 1+2 (e2/e3 never hit HBM)
    edge12_kernel<<<R, 256, 0, stream>>>(e_attr, We1 + 2 * FF * FF, We2 + 2 * FF * FF,
                                         P1, Q1, P2, Q2, A, v);
    head_kernel<<<1, 64, 0, stream>>>(v, W1, b1, W2, b2, W3, b3, out);
}

// Round 3
// 414.193 us; speedup vs baseline: 4.8234x; 4.8234x over previous
//
#include <hip/hip_runtime.h>

#define BB 8
#define NN 256
#define FF 64
#define ET 128  // edges per tile (half a row)

// ---------------------------------------------------------------------------
// pq: P[r] = be + x[r]@We[0:64], Q[r] = x[r]@We[64:128].  Also zeroes agg.
// 4 rows/block.
// ---------------------------------------------------------------------------
__global__ __launch_bounds__(256) void pq_kernel(
    const float* __restrict__ x, const float* __restrict__ We,
    const float* __restrict__ be, float* __restrict__ P, float* __restrict__ Q,
    float* __restrict__ agg)
{
    const int rl = threadIdx.x >> 6, f = threadIdx.x & 63;
    const int r = blockIdx.x * 4 + rl;
    __shared__ float xs[4][FF];
    xs[rl][f] = x[r * FF + f];
    agg[r * FF + f] = 0.f;  // pre-zero for edge0's atomics
    __syncthreads();
    float p = be[f], q = 0.f;
#pragma unroll
    for (int k = 0; k < FF; ++k) {
        const float xv = xs[rl][k];
        p = fmaf(xv, We[k * FF + f], p);
        q = fmaf(xv, We[(FF + k) * FF + f], q);
    }
    P[r * FF + f] = p;
    Q[r * FF + f] = q;
}

// ---------------------------------------------------------------------------
// layer-0 edge kernel: one block per 128-edge tile (2 blocks per row i).
// In-place on e_attr. Writes e_out tile; atomicAdd partial row-sums to agg.
// Thread (tf, tj): 8 f (f0=8*tf) x 4 edges (e = 2*tj + 64*m + p).
// ---------------------------------------------------------------------------
__global__ __launch_bounds__(256) void edge0_kernel(
    const float* __restrict__ e_in, const float* __restrict__ Wc,
    const float* __restrict__ P, const float* __restrict__ Q,
    const int* __restrict__ A, float* __restrict__ e_out,
    float* __restrict__ agg)
{
    __shared__ float Wl[FF * FF];   // 16 KB
    __shared__ float el[FF * ET];   // 32 KB  [k][e]
    __shared__ float Al[ET];
    __shared__ float Pl[FF];
    __shared__ float red[FF];

    const int tid = threadIdx.x;
    const int bt  = blockIdx.x;
    const int bi  = bt >> 1;          // row b*256+i
    const int b   = bi >> 8;
    const int j0  = (bt & 1) << 7;    // 0 or 128

    {   // stage W (b128 stores, standard pattern)
        const float4* Ws = (const float4*)Wc;
        float4*       Wd = (float4*)Wl;
#pragma unroll
        for (int m = 0; m < 4; ++m) Wd[tid + m * 256] = Ws[tid + m * 256];
    }
    if (tid < ET) Al[tid] = (float)A[bi * NN + j0 + tid];
    if (tid < FF) Pl[tid] = P[bi * FF + tid];

    {   // stage e tile: thread owns (edge = tid/2, k-half = 32*(tid&1))
        const int et = tid >> 1, kh = (tid & 1) * 32;
        const float4* src = (const float4*)(e_in + ((size_t)bi * NN + j0 + et) * FF + kh);
        float4 v[8];
#pragma unroll
        for (int i = 0; i < 8; ++i) v[i] = src[i];
#pragma unroll
        for (int i = 0; i < 8; ++i) {
            el[(kh + 4 * i + 0) * ET + et] = v[i].x;   // bank = et%32 -> 2-way, free
            el[(kh + 4 * i + 1) * ET + et] = v[i].y;
            el[(kh + 4 * i + 2) * ET + et] = v[i].z;
            el[(kh + 4 * i + 3) * ET + et] = v[i].w;
        }
    }
    __syncthreads();

    const int tj = tid & 31, tf = tid >> 5;
    const int f0 = tf * 8;

    float acc[4][8];
#pragma unroll
    for (int a = 0; a < 4; ++a)
#pragma unroll
        for (int c = 0; c < 8; ++c) acc[a][c] = 0.f;

#pragma unroll 8
    for (int k = 0; k < FF; ++k) {
        const float4 w0 = *(const float4*)&Wl[k * FF + f0];      // broadcast, free
        const float4 w1 = *(const float4*)&Wl[k * FF + f0 + 4];
        const float wv[8] = {w0.x, w0.y, w0.z, w0.w, w1.x, w1.y, w1.z, w1.w};
#pragma unroll
        for (int m = 0; m < 2; ++m) {
            const float2 ev = *(const float2*)&el[k * ET + 2 * tj + 64 * m];
#pragma unroll
            for (int ff = 0; ff < 8; ++ff) {
                acc[2 * m][ff]     = fmaf(ev.x, wv[ff], acc[2 * m][ff]);
                acc[2 * m + 1][ff] = fmaf(ev.y, wv[ff], acc[2 * m + 1][ff]);
            }
        }
    }

    // epilogue: relu(acc + P[i] + Q[j]) * A, write out, partial sum over edges
    float psum[8];
#pragma unroll
    for (int ff = 0; ff < 8; ++ff) psum[ff] = 0.f;
    const float* Qb = Q + (size_t)b * NN * FF;
#pragma unroll
    for (int m = 0; m < 2; ++m)
#pragma unroll
        for (int p = 0; p < 2; ++p) {
            const int ee = 2 * tj + 64 * m + p;
            const int jj = 2 * m + p;
            const int j  = j0 + ee;
            const float a = Al[ee];
            const float4 q0 = *(const float4*)(Qb + j * FF + f0);
            const float4 q1 = *(const float4*)(Qb + j * FF + f0 + 4);
            const float qv[8] = {q0.x, q0.y, q0.z, q0.w, q1.x, q1.y, q1.z, q1.w};
            float r[8];
#pragma unroll
            for (int ff = 0; ff < 8; ++ff) {
                r[ff] = fmaxf(acc[jj][ff] + Pl[f0 + ff] + qv[ff], 0.f) * a;
                psum[ff] += r[ff];
            }
            float* orow = e_out + ((size_t)bi * NN + j) * FF;
            *(float4*)(orow + f0)     = make_float4(r[0], r[1], r[2], r[3]);
            *(float4*)(orow + f0 + 4) = make_float4(r[4], r[5], r[6], r[7]);
        }
    // half-wave (32-lane, same f0) reduce; lane tj==0 writes its f-slice
#pragma unroll
    for (int ff = 0; ff < 8; ++ff) {
#pragma unroll
        for (int off = 16; off > 0; off >>= 1)
            psum[ff] += __shfl_down(psum[ff], off, 32);
    }
    if (tj == 0) {
#pragma unroll
        for (int ff = 0; ff < 8; ++ff) red[f0 + ff] = psum[ff];
    }
    __syncthreads();
    if (tid < FF) atomicAdd(&agg[bi * FF + tid], red[tid]);
}

// ---------------------------------------------------------------------------
// fused node-update + deg + pq(1,2) + zero v.  4 rows/block (4 waves).
// agg here is the raw row-sum from edge0; divide by deg = max(sum A,1).
// ---------------------------------------------------------------------------
__global__ __launch_bounds__(256) void nodepq_kernel(
    const float* __restrict__ x, const float* __restrict__ agg,
    const int* __restrict__ A,
    const float* __restrict__ Wn, const float* __restrict__ bn,
    const float* __restrict__ We1, const float* __restrict__ be1,
    const float* __restrict__ We2, const float* __restrict__ be2,
    float* __restrict__ P1, float* __restrict__ Q1,
    float* __restrict__ P2, float* __restrict__ Q2, float* __restrict__ v)
{
    const int rl = threadIdx.x >> 6, f = threadIdx.x & 63;
    const int r = blockIdx.x * 4 + rl;
    __shared__ float s[4][2 * FF];
    __shared__ float x1s[4][FF];

    // deg: wave rl sums A[r][0..255]
    float da = (float)A[r * NN + f] + (float)A[r * NN + f + 64] +
               (float)A[r * NN + f + 128] + (float)A[r * NN + f + 192];
#pragma unroll
    for (int off = 32; off > 0; off >>= 1) da += __shfl_down(da, off, 64);
    const float deg = fmaxf(__shfl(da, 0, 64), 1.0f);

    s[rl][f]      = x[r * FF + f];
    s[rl][FF + f] = agg[r * FF + f] / deg;
    if (blockIdx.x == 0) {  // zero v for edge12's atomics
        v[threadIdx.x] = 0.f;
        v[256 + threadIdx.x] = 0.f;
    }
    __syncthreads();
    float a = bn[f];
#pragma unroll
    for (int k = 0; k < 2 * FF; ++k) a = fmaf(s[rl][k], Wn[k * FF + f], a);
    x1s[rl][f] = fmaxf(a, 0.f);
    __syncthreads();
    float p1 = be1[f], q1 = 0.f, p2 = be2[f], q2 = 0.f;
#pragma unroll
    for (int k = 0; k < FF; ++k) {
        const float xv = x1s[rl][k];
        p1 = fmaf(xv, We1[k * FF + f], p1);
        q1 = fmaf(xv, We1[(FF + k) * FF + f], q1);
        p2 = fmaf(xv, We2[k * FF + f], p2);
        q2 = fmaf(xv, We2[(FF + k) * FF + f], q2);
    }
    P1[r * FF + f] = p1;  Q1[r * FF + f] = q1;
    P2[r * FF + f] = p2;  Q2[r * FF + f] = q2;
}

// ---------------------------------------------------------------------------
// fused layers 1+2 per 128-edge tile. e2 lives only in LDS (overwrites e1
// tile); e3 reduced straight to v. acc (32 regs) dead before acc2 is live.
// ---------------------------------------------------------------------------
__global__ __launch_bounds__(256) void edge12_kernel(
    const float* __restrict__ e_in,
    const float* __restrict__ Wc1, const float* __restrict__ Wc2,
    const float* __restrict__ P1, const float* __restrict__ Q1,
    const float* __restrict__ P2, const float* __restrict__ Q2,
    const int* __restrict__ A, float* __restrict__ v)
{
    __shared__ float Wl[FF * FF];
    __shared__ float el[FF * ET];
    __shared__ float Al[ET];
    __shared__ float Pl1[FF], Pl2[FF];
    __shared__ float red[FF];

    const int tid = threadIdx.x;
    const int bt  = blockIdx.x;
    const int bi  = bt >> 1;
    const int b   = bi >> 8;
    const int j0  = (bt & 1) << 7;

    {
        const float4* Ws = (const float4*)Wc1;
        float4*       Wd = (float4*)Wl;
#pragma unroll
        for (int m = 0; m < 4; ++m) Wd[tid + m * 256] = Ws[tid + m * 256];
    }
    if (tid < ET) Al[tid] = (float)A[bi * NN + j0 + tid];
    if (tid < FF) { Pl1[tid] = P1[bi * FF + tid]; Pl2[tid] = P2[bi * FF + tid]; }

    {
        const int et = tid >> 1, kh = (tid & 1) * 32;
        const float4* src = (const float4*)(e_in + ((size_t)bi * NN + j0 + et) * FF + kh);
        float4 vv[8];
#pragma unroll
        for (int i = 0; i < 8; ++i) vv[i] = src[i];
#pragma unroll
        for (int i = 0; i < 8; ++i) {
            el[(kh + 4 * i + 0) * ET + et] = vv[i].x;
            el[(kh + 4 * i + 1) * ET + et] = vv[i].y;
            el[(kh + 4 * i + 2) * ET + et] = vv[i].z;
            el[(kh + 4 * i + 3) * ET + et] = vv[i].w;
        }
    }
    __syncthreads();

    const int tj = tid & 31, tf = tid >> 5;
    const int f0 = tf * 8;

    // ---------------- GEMM1 ----------------
    float acc[4][8];
#pragma unroll
    for (int a = 0; a < 4; ++a)
#pragma unroll
        for (int c = 0; c < 8; ++c) acc[a][c] = 0.f;

#pragma unroll 8
    for (int k = 0; k < FF; ++k) {
        const float4 w0 = *(const float4*)&Wl[k * FF + f0];
        const float4 w1 = *(const float4*)&Wl[k * FF + f0 + 4];
        const float wv[8] = {w0.x, w0.y, w0.z, w0.w, w1.x, w1.y, w1.z, w1.w};
#pragma unroll
        for (int m = 0; m < 2; ++m) {
            const float2 ev = *(const float2*)&el[k * ET + 2 * tj + 64 * m];
#pragma unroll
            for (int ff = 0; ff < 8; ++ff) {
                acc[2 * m][ff]     = fmaf(ev.x, wv[ff], acc[2 * m][ff]);
                acc[2 * m + 1][ff] = fmaf(ev.y, wv[ff], acc[2 * m + 1][ff]);
            }
        }
    }

    // epilogue 1 -> e2 fragment in acc
    {
        const float* Q1b = Q1 + (size_t)b * NN * FF;
#pragma unroll
        for (int m = 0; m < 2; ++m)
#pragma unroll
            for (int p = 0; p < 2; ++p) {
                const int ee = 2 * tj + 64 * m + p;
                const int jj = 2 * m + p;
                const int j  = j0 + ee;
                const float a = Al[ee];
                const float4 q0 = *(const float4*)(Q1b + j * FF + f0);
                const float4 q1 = *(const float4*)(Q1b + j * FF + f0 + 4);
                const float qv[8] = {q0.x, q0.y, q0.z, q0.w, q1.x, q1.y, q1.z, q1.w};
#pragma unroll
                for (int ff = 0; ff < 8; ++ff)
                    acc[jj][ff] = fmaxf(acc[jj][ff] + Pl1[f0 + ff] + qv[ff], 0.f) * a;
            }
    }
    __syncthreads();  // all GEMM1 reads of el/Wl done

    {   // restage W2
        const float4* Ws = (const float4*)Wc2;
        float4*       Wd = (float4*)Wl;
#pragma unroll
        for (int m = 0; m < 4; ++m) Wd[tid + m * 256] = Ws[tid + m * 256];
    }
    // write e2 into el[k=f][e]; float2 over adjacent edges (p=0,1). 2-way, free.
#pragma unroll
    for (int ff = 0; ff < 8; ++ff)
#pragma unroll
        for (int m = 0; m < 2; ++m)
            *(float2*)&el[(f0 + ff) * ET + 2 * tj + 64 * m] =
                make_float2(acc[2 * m][ff], acc[2 * m + 1][ff]);
    __syncthreads();

    // ---------------- GEMM2 ----------------
    float acc2[4][8];
#pragma unroll
    for (int a = 0; a < 4; ++a)
#pragma unroll
        for (int c = 0; c < 8; ++c) acc2[a][c] = 0.f;

#pragma unroll 8
    for (int k = 0; k < FF; ++k) {
        const float4 w0 = *(const float4*)&Wl[k * FF + f0];
        const float4 w1 = *(const float4*)&Wl[k * FF + f0 + 4];
        const float wv[8] = {w0.x, w0.y, w0.z, w0.w, w1.x, w1.y, w1.z, w1.w};
#pragma unroll
        for (int m = 0; m < 2; ++m) {
            const float2 ev = *(const float2*)&el[k * ET + 2 * tj + 64 * m];
#pragma unroll
            for (int ff = 0; ff < 8; ++ff) {
                acc2[2 * m][ff]     = fmaf(ev.x, wv[ff], acc2[2 * m][ff]);
                acc2[2 * m + 1][ff] = fmaf(ev.y, wv[ff], acc2[2 * m + 1][ff]);
            }
        }
    }

    // epilogue 2: reduce relu(acc2+P2+Q2)*A over edges
    float psum[8];
#pragma unroll
    for (int ff = 0; ff < 8; ++ff) psum[ff] = 0.f;
    const float* Q2b = Q2 + (size_t)b * NN * FF;
#pragma unroll
    for (int m = 0; m < 2; ++m)
#pragma unroll
        for (int p = 0; p < 2; ++p) {
            const int ee = 2 * tj + 64 * m + p;
            const int jj = 2 * m + p;
            const int j  = j0 + ee;
            const float a = Al[ee];
            const float4 q0 = *(const float4*)(Q2b + j * FF + f0);
            const float4 q1 = *(const float4*)(Q2b + j * FF + f0 + 4);
            const float qv[8] = {q0.x, q0.y, q0.z, q0.w, q1.x, q1.y, q1.z, q1.w};
#pragma unroll
            for (int ff = 0; ff < 8; ++ff)
                psum[ff] += fmaxf(acc2[jj][ff] + Pl2[f0 + ff] + qv[ff], 0.f) * a;
        }
#pragma unroll
    for (int ff = 0; ff < 8; ++ff) {
#pragma unroll
        for (int off = 16; off > 0; off >>= 1)
            psum[ff] += __shfl_down(psum[ff], off, 32);
    }
    if (tj == 0) {
#pragma unroll
        for (int ff = 0; ff < 8; ++ff) red[f0 + ff] = psum[ff];
    }
    __syncthreads();
    if (tid < FF) atomicAdd(&v[b * FF + tid], red[tid]);
}

// ---------------------------------------------------------------------------
// head: v/65536 -> relu(@W1+b1) -> relu(@W2+b2) -> @W3+b3
// ---------------------------------------------------------------------------
__global__ __launch_bounds__(64) void head_kernel(
    const float* __restrict__ vsum, const float* __restrict__ W1,
    const float* __restrict__ b1, const float* __restrict__ W2,
    const float* __restrict__ b2, const float* __restrict__ W3,
    const float* __restrict__ b3, float* __restrict__ out)
{
    const int f = threadIdx.x;
    __shared__ float hv[BB][FF];
    __shared__ float h1[BB][FF];
#pragma unroll
    for (int b = 0; b < BB; ++b) hv[b][f] = vsum[b * FF + f] * (1.0f / 65536.0f);
    __syncthreads();
#pragma unroll
    for (int b = 0; b < BB; ++b) {
        float acc = b1[f];
#pragma unroll
        for (int k = 0; k < FF; ++k) acc = fmaf(hv[b][k], W1[k * FF + f], acc);
        h1[b][f] = fmaxf(acc, 0.f);
    }
    __syncthreads();
#pragma unroll
    for (int b = 0; b < BB; ++b) {
        float acc = b2[f];
#pragma unroll
        for (int k = 0; k < FF; ++k) acc = fmaf(h1[b][k], W2[k * FF + f], acc);
        hv[b][f] = fmaxf(acc, 0.f);
    }
    __syncthreads();
#pragma unroll
    for (int b = 0; b < BB; ++b) {
        float p = hv[b][f] * W3[f];
#pragma unroll
        for (int off = 32; off > 0; off >>= 1) p += __shfl_down(p, off);
        if (f == 0) out[b] = p + b3[0];
    }
}

// ---------------------------------------------------------------------------
extern "C" void kernel_launch(void* const* d_in, const int* in_sizes, int n_in,
                              void* d_out, int out_size, void* d_ws, size_t ws_size,
                              hipStream_t stream)
{
    const int*   A      = (const int*)d_in[0];
    const float* x      = (const float*)d_in[1];
    float*       e_attr = (float*)d_in[2];  // in-place (harness restores)

    const float* We0 = (const float*)d_in[3];
    const float* be0 = (const float*)d_in[4];
    const float* Wn0 = (const float*)d_in[5];
    const float* bn0 = (const float*)d_in[6];
    const float* We1 = (const float*)d_in[7];
    const float* be1 = (const float*)d_in[8];
    const float* We2 = (const float*)d_in[11];
    const float* be2 = (const float*)d_in[12];
    const float* W1 = (const float*)d_in[15];
    const float* b1 = (const float*)d_in[16];
    const float* W2 = (const float*)d_in[17];
    const float* b2 = (const float*)d_in[18];
    const float* W3 = (const float*)d_in[19];
    const float* b3 = (const float*)d_in[20];
    float* out = (float*)d_out;
    (void)in_sizes; (void)n_in; (void)out_size; (void)ws_size;

    const int R = BB * NN;   // 2048 rows
    float* P1  = (float*)d_ws;        // also P0
    float* Q1  = P1 + R * FF;         // also Q0
    float* P2  = Q1 + R * FF;
    float* Q2  = P2 + R * FF;
    float* agg = Q2 + R * FF;
    float* v   = agg + R * FF;        // 512 floats

    const int EB = 2 * R;    // 4096 edge tiles

    pq_kernel<<<R / 4, 256, 0, stream>>>(x, We0, be0, P1, Q1, agg);
    edge0_kernel<<<EB, 256, 0, stream>>>(e_attr, We0 + 2 * FF * FF, P1, Q1, A,
                                         e_attr, agg);
    nodepq_kernel<<<R / 4, 256, 0, stream>>>(x, agg, A, Wn0, bn0, We1, be1,
                                             We2, be2, P1, Q1, P2, Q2, v);
    edge12_kernel<<<EB, 256, 0, stream>>>(e_attr, We1 + 2 * FF * FF,
                                          We2 + 2 * FF * FF, P1, Q1, P2, Q2, A, v);
    head_kernel<<<1, 64, 0, stream>>>(v, W1, b1, W2, b2, W3, b3, out);
}

// Round 4
// 361.672 us; speedup vs baseline: 5.5238x; 1.1452x over previous
//
#include <hip/hip_runtime.h>

#define BB 8
#define NN 256
#define FF 64

typedef float f32x4 __attribute__((ext_vector_type(4)));
typedef short s16x8 __attribute__((ext_vector_type(8)));
typedef unsigned short u16;

#define MFMA_BF16(a, b, c) __builtin_amdgcn_mfma_f32_16x16x32_bf16(a, b, c, 0, 0, 0)

// fp32 -> bf16 round-to-nearest-even
__device__ inline u16 f2bf(float x) {
    unsigned u = __float_as_uint(x);
    u += 0x7FFFu + ((u >> 16) & 1u);
    return (u16)(u >> 16);
}
__device__ inline float bf2f(u16 h) { return __uint_as_float(((unsigned)h) << 16); }

__device__ inline s16x8 cvt_a(float4 v0, float4 v1) {
    s16x8 a;
    a[0] = (short)f2bf(v0.x); a[1] = (short)f2bf(v0.y);
    a[2] = (short)f2bf(v0.z); a[3] = (short)f2bf(v0.w);
    a[4] = (short)f2bf(v1.x); a[5] = (short)f2bf(v1.y);
    a[6] = (short)f2bf(v1.z); a[7] = (short)f2bf(v1.w);
    return a;
}

// ---------------------------------------------------------------------------
// Build per-layer W LDS images: transposed [f][k], k-chunks XOR-swizzled
// (chunk slot s = c ^ (f&7)), split hi/lo bf16. Image = 4096 u16 each.
// grid 3 (one block per layer).
// ---------------------------------------------------------------------------
__global__ __launch_bounds__(256) void wprep_kernel(
    const float* __restrict__ We0, const float* __restrict__ We1,
    const float* __restrict__ We2, u16* __restrict__ wimg)
{
    const float* src =
        (blockIdx.x == 0 ? We0 : (blockIdx.x == 1 ? We1 : We2)) + 2 * FF * FF;
    u16* hi = wimg + blockIdx.x * 8192;
    u16* lo = hi + 4096;
    for (int idx = threadIdx.x; idx < 4096; idx += 256) {
        const int f = idx >> 6, rem = idx & 63, cs = rem >> 3, j = rem & 7;
        const int k = ((cs ^ (f & 7)) << 3) | j;
        const float wv = src[k * FF + f];
        const u16 h = f2bf(wv);
        hi[idx] = h;
        lo[idx] = f2bf(wv - bf2f(h));
    }
}

// ---------------------------------------------------------------------------
// pq: P[r] = be + x[r]@We[0:64], Q[r] = x[r]@We[64:128]. Also zeroes agg.
// ---------------------------------------------------------------------------
__global__ __launch_bounds__(256) void pq_kernel(
    const float* __restrict__ x, const float* __restrict__ We,
    const float* __restrict__ be, float* __restrict__ P, float* __restrict__ Q,
    float* __restrict__ agg)
{
    const int rl = threadIdx.x >> 6, f = threadIdx.x & 63;
    const int r = blockIdx.x * 4 + rl;
    __shared__ float xs[4][FF];
    xs[rl][f] = x[r * FF + f];
    agg[r * FF + f] = 0.f;
    __syncthreads();
    float p = be[f], q = 0.f;
#pragma unroll
    for (int k = 0; k < FF; ++k) {
        const float xv = xs[rl][k];
        p = fmaf(xv, We[k * FF + f], p);
        q = fmaf(xv, We[(FF + k) * FF + f], q);
    }
    P[r * FF + f] = p;
    Q[r * FF + f] = q;
}

// ---------------------------------------------------------------------------
// layer-0 edge kernel (MFMA). One block per 128-edge tile.
// wave w owns e in [32w,32w+32) x all 64 f: 2x4 C-tiles of 16x16.
// A-frags straight from global (fp32 -> bf16), B from swizzled LDS W image.
// ---------------------------------------------------------------------------
__global__ __launch_bounds__(256) void edge0_kernel(
    const float* __restrict__ e_in, const u16* __restrict__ whi,
    const u16* __restrict__ wlo, const float* __restrict__ P,
    const float* __restrict__ Q, const int* __restrict__ A,
    float* __restrict__ e_out, float* __restrict__ agg)
{
    __shared__ u16 Whl[4096], Wll[4096];
    __shared__ float Al[128], Pl[64];

    const int tid = threadIdx.x;
    const int bt  = blockIdx.x;
    const int bi  = bt >> 1;
    const int b   = bi >> 8;
    const int j0  = (bt & 1) << 7;

#pragma unroll
    for (int m = 0; m < 2; ++m) {
        ((uint4*)Whl)[tid + 256 * m] = ((const uint4*)whi)[tid + 256 * m];
        ((uint4*)Wll)[tid + 256 * m] = ((const uint4*)wlo)[tid + 256 * m];
    }
    if (tid < 128) Al[tid] = (float)A[bi * NN + j0 + tid];
    if (tid < 64)  Pl[tid] = P[bi * FF + tid];

    const int w = tid >> 6, lane = tid & 63;
    const int quad = lane >> 4, l15 = lane & 15, l7 = lane & 7;
    const int e_base = 32 * w;

    const float* erow = e_in + ((size_t)bi * NN + j0) * FF;

    // A-fragments from global: A[e = l15][k = quad*8 + j]
    s16x8 afr[2][2];
#pragma unroll
    for (int ks = 0; ks < 2; ++ks)
#pragma unroll
        for (int et = 0; et < 2; ++et) {
            const float* p = erow + (e_base + et * 16 + l15) * FF + ks * 32 + quad * 8;
            afr[ks][et] = cvt_a(*(const float4*)p, *(const float4*)(p + 4));
        }

    // Q prefetch: lane's C positions: e = e_base+et*16+quad*4+r, f = ft*16+l15
    float qv[2][4][4];
    const float* Qb = Q + (size_t)b * NN * FF;
#pragma unroll
    for (int et = 0; et < 2; ++et)
#pragma unroll
        for (int ft = 0; ft < 4; ++ft)
#pragma unroll
            for (int r = 0; r < 4; ++r)
                qv[et][ft][r] =
                    Qb[(j0 + e_base + et * 16 + quad * 4 + r) * FF + ft * 16 + l15];

    __syncthreads();

    f32x4 acc[2][4];
#pragma unroll
    for (int et = 0; et < 2; ++et)
#pragma unroll
        for (int ft = 0; ft < 4; ++ft) acc[et][ft] = (f32x4){0.f, 0.f, 0.f, 0.f};

#pragma unroll
    for (int ks = 0; ks < 2; ++ks)
#pragma unroll
        for (int ft = 0; ft < 4; ++ft) {
            const int f  = ft * 16 + l15;
            const int ca = (ks * 4 + quad) ^ l7;
            const s16x8 bh = *(const s16x8*)&Whl[f * 64 + ca * 8];
            const s16x8 bl = *(const s16x8*)&Wll[f * 64 + ca * 8];
#pragma unroll
            for (int et = 0; et < 2; ++et) {
                acc[et][ft] = MFMA_BF16(afr[ks][et], bh, acc[et][ft]);
                acc[et][ft] = MFMA_BF16(afr[ks][et], bl, acc[et][ft]);
            }
        }

    // epilogue: C[row = quad*4+r (+16et+32w)][col = l15 (+16ft)]
    float psum[4] = {0.f, 0.f, 0.f, 0.f};
#pragma unroll
    for (int et = 0; et < 2; ++et)
#pragma unroll
        for (int ft = 0; ft < 4; ++ft)
#pragma unroll
            for (int r = 0; r < 4; ++r) {
                const int el = e_base + et * 16 + quad * 4 + r;
                const int f  = ft * 16 + l15;
                const float val = acc[et][ft][r] + Pl[f] + qv[et][ft][r];
                const float rv  = fmaxf(val, 0.f) * Al[el];
                e_out[((size_t)bi * NN + j0 + el) * FF + f] = rv;
                psum[ft] += rv;
            }
#pragma unroll
    for (int ft = 0; ft < 4; ++ft) {
        psum[ft] += __shfl_down(psum[ft], 32);
        psum[ft] += __shfl_down(psum[ft], 16);
    }
    if (lane < 16) {
#pragma unroll
        for (int ft = 0; ft < 4; ++ft)
            atomicAdd(&agg[bi * FF + ft * 16 + l15], psum[ft]);
    }
}

// ---------------------------------------------------------------------------
// fused node-update + deg + pq(1,2) + zero v.
// ---------------------------------------------------------------------------
__global__ __launch_bounds__(256) void nodepq_kernel(
    const float* __restrict__ x, const float* __restrict__ agg,
    const int* __restrict__ A,
    const float* __restrict__ Wn, const float* __restrict__ bn,
    const float* __restrict__ We1, const float* __restrict__ be1,
    const float* __restrict__ We2, const float* __restrict__ be2,
    float* __restrict__ P1, float* __restrict__ Q1,
    float* __restrict__ P2, float* __restrict__ Q2, float* __restrict__ v)
{
    const int rl = threadIdx.x >> 6, f = threadIdx.x & 63;
    const int r = blockIdx.x * 4 + rl;
    __shared__ float s[4][2 * FF];
    __shared__ float x1s[4][FF];

    float da = (float)A[r * NN + f] + (float)A[r * NN + f + 64] +
               (float)A[r * NN + f + 128] + (float)A[r * NN + f + 192];
#pragma unroll
    for (int off = 32; off > 0; off >>= 1) da += __shfl_down(da, off, 64);
    const float deg = fmaxf(__shfl(da, 0, 64), 1.0f);

    s[rl][f]      = x[r * FF + f];
    s[rl][FF + f] = agg[r * FF + f] / deg;
    if (blockIdx.x == 0) {
        v[threadIdx.x] = 0.f;
        v[256 + threadIdx.x] = 0.f;
    }
    __syncthreads();
    float a = bn[f];
#pragma unroll
    for (int k = 0; k < 2 * FF; ++k) a = fmaf(s[rl][k], Wn[k * FF + f], a);
    x1s[rl][f] = fmaxf(a, 0.f);
    __syncthreads();
    float p1 = be1[f], q1 = 0.f, p2 = be2[f], q2 = 0.f;
#pragma unroll
    for (int k = 0; k < FF; ++k) {
        const float xv = x1s[rl][k];
        p1 = fmaf(xv, We1[k * FF + f], p1);
        q1 = fmaf(xv, We1[(FF + k) * FF + f], q1);
        p2 = fmaf(xv, We2[k * FF + f], p2);
        q2 = fmaf(xv, We2[(FF + k) * FF + f], q2);
    }
    P1[r * FF + f] = p1;  Q1[r * FF + f] = q1;
    P2[r * FF + f] = p2;  Q2[r * FF + f] = q2;
}

// ---------------------------------------------------------------------------
// fused layers 1+2 (MFMA). GEMM1 A from global; e2 transposed C->A layout
// through a 16 KB LDS image (bf16, XOR-swizzled); GEMM2; reduce to v.
// ---------------------------------------------------------------------------
__global__ __launch_bounds__(256) void edge12_kernel(
    const float* __restrict__ e_in,
    const u16* __restrict__ w1hi, const u16* __restrict__ w1lo,
    const u16* __restrict__ w2hi, const u16* __restrict__ w2lo,
    const float* __restrict__ P1, const float* __restrict__ Q1,
    const float* __restrict__ P2, const float* __restrict__ Q2,
    const int* __restrict__ A, float* __restrict__ v)
{
    __shared__ u16 W1h[4096], W1l[4096], W2h[4096], W2l[4096];
    __shared__ u16 E2[128 * 64];
    __shared__ float Al[128], Pl1[64], Pl2[64], red[64];

    const int tid = threadIdx.x;
    const int bt  = blockIdx.x;
    const int bi  = bt >> 1;
    const int b   = bi >> 8;
    const int j0  = (bt & 1) << 7;

#pragma unroll
    for (int m = 0; m < 2; ++m) {
        ((uint4*)W1h)[tid + 256 * m] = ((const uint4*)w1hi)[tid + 256 * m];
        ((uint4*)W1l)[tid + 256 * m] = ((const uint4*)w1lo)[tid + 256 * m];
        ((uint4*)W2h)[tid + 256 * m] = ((const uint4*)w2hi)[tid + 256 * m];
        ((uint4*)W2l)[tid + 256 * m] = ((const uint4*)w2lo)[tid + 256 * m];
    }
    if (tid < 128) Al[tid] = (float)A[bi * NN + j0 + tid];
    if (tid < 64) {
        Pl1[tid] = P1[bi * FF + tid];
        Pl2[tid] = P2[bi * FF + tid];
        red[tid] = 0.f;
    }

    const int w = tid >> 6, lane = tid & 63;
    const int quad = lane >> 4, l15 = lane & 15, l7 = lane & 7;
    const int e_base = 32 * w;

    const float* erow = e_in + ((size_t)bi * NN + j0) * FF;

    s16x8 afr[2][2];
#pragma unroll
    for (int ks = 0; ks < 2; ++ks)
#pragma unroll
        for (int et = 0; et < 2; ++et) {
            const float* p = erow + (e_base + et * 16 + l15) * FF + ks * 32 + quad * 8;
            afr[ks][et] = cvt_a(*(const float4*)p, *(const float4*)(p + 4));
        }

    float qv[2][4][4];
    {
        const float* Q1b = Q1 + (size_t)b * NN * FF;
#pragma unroll
        for (int et = 0; et < 2; ++et)
#pragma unroll
            for (int ft = 0; ft < 4; ++ft)
#pragma unroll
                for (int r = 0; r < 4; ++r)
                    qv[et][ft][r] =
                        Q1b[(j0 + e_base + et * 16 + quad * 4 + r) * FF + ft * 16 + l15];
    }

    __syncthreads();

    // ---------------- GEMM1 ----------------
    f32x4 acc[2][4];
#pragma unroll
    for (int et = 0; et < 2; ++et)
#pragma unroll
        for (int ft = 0; ft < 4; ++ft) acc[et][ft] = (f32x4){0.f, 0.f, 0.f, 0.f};

#pragma unroll
    for (int ks = 0; ks < 2; ++ks)
#pragma unroll
        for (int ft = 0; ft < 4; ++ft) {
            const int f  = ft * 16 + l15;
            const int ca = (ks * 4 + quad) ^ l7;
            const s16x8 bh = *(const s16x8*)&W1h[f * 64 + ca * 8];
            const s16x8 bl = *(const s16x8*)&W1l[f * 64 + ca * 8];
#pragma unroll
            for (int et = 0; et < 2; ++et) {
                acc[et][ft] = MFMA_BF16(afr[ks][et], bh, acc[et][ft]);
                acc[et][ft] = MFMA_BF16(afr[ks][et], bl, acc[et][ft]);
            }
        }

    // epilogue 1: e2 = relu(acc + P1 + Q1) * A  -> bf16 -> LDS A-layout image
#pragma unroll
    for (int et = 0; et < 2; ++et)
#pragma unroll
        for (int ft = 0; ft < 4; ++ft)
#pragma unroll
            for (int r = 0; r < 4; ++r) {
                const int el = e_base + et * 16 + quad * 4 + r;
                const int f  = ft * 16 + l15;
                const float val = acc[et][ft][r] + Pl1[f] + qv[et][ft][r];
                const float rv  = fmaxf(val, 0.f) * Al[el];
                const int c  = f >> 3;           // k-chunk (k = f for GEMM2)
                const int cs = c ^ (el & 7);
                E2[el * 64 + cs * 8 + l7] = f2bf(rv);
            }

    // Q2 prefetch (in flight across the barrier)
    {
        const float* Q2b = Q2 + (size_t)b * NN * FF;
#pragma unroll
        for (int et = 0; et < 2; ++et)
#pragma unroll
            for (int ft = 0; ft < 4; ++ft)
#pragma unroll
                for (int r = 0; r < 4; ++r)
                    qv[et][ft][r] =
                        Q2b[(j0 + e_base + et * 16 + quad * 4 + r) * FF + ft * 16 + l15];
    }

    __syncthreads();

    // ---------------- GEMM2 ----------------
#pragma unroll
    for (int et = 0; et < 2; ++et)
#pragma unroll
        for (int ft = 0; ft < 4; ++ft) acc[et][ft] = (f32x4){0.f, 0.f, 0.f, 0.f};

#pragma unroll
    for (int ks = 0; ks < 2; ++ks) {
        s16x8 a2[2];
#pragma unroll
        for (int et = 0; et < 2; ++et) {
            const int e  = e_base + et * 16 + l15;
            const int ca = (ks * 4 + quad) ^ l7;  // e&7 == l7
            a2[et] = *(const s16x8*)&E2[e * 64 + ca * 8];
        }
#pragma unroll
        for (int ft = 0; ft < 4; ++ft) {
            const int f  = ft * 16 + l15;
            const int ca = (ks * 4 + quad) ^ l7;
            const s16x8 bh = *(const s16x8*)&W2h[f * 64 + ca * 8];
            const s16x8 bl = *(const s16x8*)&W2l[f * 64 + ca * 8];
#pragma unroll
            for (int et = 0; et < 2; ++et) {
                acc[et][ft] = MFMA_BF16(a2[et], bh, acc[et][ft]);
                acc[et][ft] = MFMA_BF16(a2[et], bl, acc[et][ft]);
            }
        }
    }

    // epilogue 2: reduce relu(acc + P2 + Q2)*A over edges
    float psum[4] = {0.f, 0.f, 0.f, 0.f};
#pragma unroll
    for (int et = 0; et < 2; ++et)
#pragma unroll
        for (int ft = 0; ft < 4; ++ft)
#pragma unroll
            for (int r = 0; r < 4; ++r) {
                const int el = e_base + et * 16 + quad * 4 + r;
                const int f  = ft * 16 + l15;
                const float val = acc[et][ft][r] + Pl2[f] + qv[et][ft][r];
                psum[ft] += fmaxf(val, 0.f) * Al[el];
            }
#pragma unroll
    for (int ft = 0; ft < 4; ++ft) {
        psum[ft] += __shfl_down(psum[ft], 32);
        psum[ft] += __shfl_down(psum[ft], 16);
    }
    if (lane < 16) {
#pragma unroll
        for (int ft = 0; ft < 4; ++ft)
            atomicAdd(&red[ft * 16 + l15], psum[ft]);
    }
    __syncthreads();
    if (tid < 64) atomicAdd(&v[b * FF + tid], red[tid]);
}

// ---------------------------------------------------------------------------
// head: v/65536 -> relu(@W1+b1) -> relu(@W2+b2) -> @W3+b3
// ---------------------------------------------------------------------------
__global__ __launch_bounds__(64) void head_kernel(
    const float* __restrict__ vsum, const float* __restrict__ W1,
    const float* __restrict__ b1, const float* __restrict__ W2,
    const float* __restrict__ b2, const float* __restrict__ W3,
    const float* __restrict__ b3, float* __restrict__ out)
{
    const int f = threadIdx.x;
    __shared__ float hv[BB][FF];
    __shared__ float h1[BB][FF];
#pragma unroll
    for (int b = 0; b < BB; ++b) hv[b][f] = vsum[b * FF + f] * (1.0f / 65536.0f);
    __syncthreads();
#pragma unroll
    for (int b = 0; b < BB; ++b) {
        float acc = b1[f];
#pragma unroll
        for (int k = 0; k < FF; ++k) acc = fmaf(hv[b][k], W1[k * FF + f], acc);
        h1[b][f] = fmaxf(acc, 0.f);
    }
    __syncthreads();
#pragma unroll
    for (int b = 0; b < BB; ++b) {
        float acc = b2[f];
#pragma unroll
        for (int k = 0; k < FF; ++k) acc = fmaf(h1[b][k], W2[k * FF + f], acc);
        hv[b][f] = fmaxf(acc, 0.f);
    }
    __syncthreads();
#pragma unroll
    for (int b = 0; b < BB; ++b) {
        float p = hv[b][f] * W3[f];
#pragma unroll
        for (int off = 32; off > 0; off >>= 1) p += __shfl_down(p, off);
        if (f == 0) out[b] = p + b3[0];
    }
}

// ---------------------------------------------------------------------------
extern "C" void kernel_launch(void* const* d_in, const int* in_sizes, int n_in,
                              void* d_out, int out_size, void* d_ws, size_t ws_size,
                              hipStream_t stream)
{
    const int*   A      = (const int*)d_in[0];
    const float* x      = (const float*)d_in[1];
    float*       e_attr = (float*)d_in[2];  // in-place (harness restores)

    const float* We0 = (const float*)d_in[3];
    const float* be0 = (const float*)d_in[4];
    const float* Wn0 = (const float*)d_in[5];
    const float* bn0 = (const float*)d_in[6];
    const float* We1 = (const float*)d_in[7];
    const float* be1 = (const float*)d_in[8];
    const float* We2 = (const float*)d_in[11];
    const float* be2 = (const float*)d_in[12];
    const float* W1 = (const float*)d_in[15];
    const float* b1 = (const float*)d_in[16];
    const float* W2 = (const float*)d_in[17];
    const float* b2 = (const float*)d_in[18];
    const float* W3 = (const float*)d_in[19];
    const float* b3 = (const float*)d_in[20];
    float* out = (float*)d_out;
    (void)in_sizes; (void)n_in; (void)out_size; (void)ws_size;

    const int R = BB * NN;   // 2048 rows
    float* P1  = (float*)d_ws;        // also P0
    float* Q1  = P1 + R * FF;         // also Q0
    float* P2  = Q1 + R * FF;
    float* Q2  = P2 + R * FF;
    float* agg = Q2 + R * FF;
    float* v   = agg + R * FF;        // 512 floats
    u16*  wimg = (u16*)(v + 512);     // 3 layers x (4096 hi + 4096 lo)

    const int EB = 2 * R;    // 4096 edge-tile blocks

    wprep_kernel<<<3, 256, 0, stream>>>(We0, We1, We2, wimg);
    pq_kernel<<<R / 4, 256, 0, stream>>>(x, We0, be0, P1, Q1, agg);
    edge0_kernel<<<EB, 256, 0, stream>>>(e_attr, wimg, wimg + 4096, P1, Q1, A,
                                         e_attr, agg);
    nodepq_kernel<<<R / 4, 256, 0, stream>>>(x, agg, A, Wn0, bn0, We1, be1,
                                             We2, be2, P1, Q1, P2, Q2, v);
    edge12_kernel<<<EB, 256, 0, stream>>>(e_attr,
                                          wimg + 8192, wimg + 12288,
                                          wimg + 16384, wimg + 20480,
                                          P1, Q1, P2, Q2, A, v);
    head_kernel<<<1, 64, 0, stream>>>(v, W1, b1, W2, b2, W3, b3, out);
}